// Round 6
// baseline (2682.422 us; speedup 1.0000x reference)
//
#include <hip/hip_runtime.h>

// GNN encoder + GRU decoder. R6: split each batch across 8 blocks (grid=128,
// 4 receivers/block), h state ping-pongs via global with per-batch atomic
// barriers (device-scope, co-resident by construction: 105KB LDS = 1 block/CU,
// 128 blocks < 256 CUs). Fixes R5's two measured killers: 16-CU starvation and
// 6.4M LDS bank conflicts (fp32 strides 128 -> padded 132; gates 512 -> 520).
// All MFMA layouts/weight packing identical to R5 (validated, absmax 0.0039).

#define NJ 32
#define ROWS 512
#define TSTEPS 25
#define LDH 132          // f32 LDS/global row stride (132 words % 32 = 4)
#define LDK 264          // half LDS row stride for 256-wide (132 words)
#define LDE 168          // half LDS row stride for encoder input
#define LDG 520          // half LDS row stride for gates (260 words % 32 = 4)

typedef _Float16 half_t;
typedef __attribute__((ext_vector_type(8))) _Float16 half8;
typedef __attribute__((ext_vector_type(8))) short short8;
typedef __attribute__((ext_vector_type(4))) float f32x4;

// fp16 converted-weight pool offsets (in halves), as validated in R5.
#define OFF_ENC_W1T 0          // [256 j][160 k]
#define OFF_ENC_W2T 40960      // [128 j][256 k]
#define OFF_PE_W1T  73728      // [512 j][128 k]  (j<256: P, j>=256: Q)
#define OFF_PE_W2T  139264     // [128 j][256 k]
#define OFF_PN_W1T  172032     // [256 j][128 k]
#define OFF_PN_W2T  204800     // [128 j][256 k]
#define OFF_DE_W1T  237568     // [512 j][128 k]
#define OFF_DE_W2T  303104     // [128 j][256 k]
#define OFF_WGT     335872     // [512 j][288 k]
#define WTOTAL      483328

__device__ __align__(16) half_t g_wf16[WTOTAL];
__device__ __align__(16) float g_hbuf[2 * 16 * 32 * LDH];   // ping-pong h
__device__ int g_bar[16];                                   // per-batch barrier

__device__ __forceinline__ half8 h8zero() {
    half8 z;
    #pragma unroll
    for (int e = 0; e < 8; ++e) z[e] = (half_t)0.f;
    return z;
}
__device__ __forceinline__ half8 relu8(half8 x) {
    short8 s = *(short8*)&x;
    short8 m = s >> 15;
    s = s & ~m;
    return *(half8*)&s;
}
__device__ __forceinline__ half8 frag_from_f32(const float* base) {
    f32x4 a = *(const f32x4*)base;
    f32x4 c = *(const f32x4*)(base + 4);
    half8 h;
    #pragma unroll
    for (int e = 0; e < 4; ++e) { h[e] = (half_t)a[e]; h[4 + e] = (half_t)c[e]; }
    return h;
}
#define MFMA(a, b, c) __builtin_amdgcn_mfma_f32_16x16x32_f16((a), (b), (c), 0, 0, 0)

// ---------------- weight conversion + barrier reset (once per call) ----------
__global__ void convert_kernel(const float* __restrict__ enc_w1, const float* __restrict__ enc_w2,
                               const float* __restrict__ pe_w1, const float* __restrict__ pe_w2,
                               const float* __restrict__ pn_w1, const float* __restrict__ pn_w2,
                               const float* __restrict__ de_w1, const float* __restrict__ de_w2,
                               const float* __restrict__ w_hr, const float* __restrict__ w_hi,
                               const float* __restrict__ w_hn, const float* __restrict__ w_ir,
                               const float* __restrict__ w_ii, const float* __restrict__ w_in) {
    const int idx = blockIdx.x * 256 + threadIdx.x;
    if (idx < 16) g_bar[idx] = 0;
    if (idx >= WTOTAL) return;
    float v = 0.f;
    if (idx < OFF_ENC_W2T) {
        int o = idx, j = o / 160, k = o - j * 160;
        v = (k < 150) ? enc_w1[k * 256 + j] : 0.f;
    } else if (idx < OFF_PE_W1T) {
        int o = idx - OFF_ENC_W2T, j = o >> 8, k = o & 255;
        v = enc_w2[k * 128 + j];
    } else if (idx < OFF_PE_W2T) {
        int o = idx - OFF_PE_W1T, j = o >> 7, k = o & 127;
        v = pe_w1[(k + ((j >= 256) ? 128 : 0)) * 256 + (j & 255)];
    } else if (idx < OFF_PN_W1T) {
        int o = idx - OFF_PE_W2T, j = o >> 8, k = o & 255;
        v = pe_w2[k * 128 + j];
    } else if (idx < OFF_PN_W2T) {
        int o = idx - OFF_PN_W1T, j = o >> 7, k = o & 127;
        v = pn_w1[k * 256 + j];
    } else if (idx < OFF_DE_W1T) {
        int o = idx - OFF_PN_W2T, j = o >> 8, k = o & 255;
        v = pn_w2[k * 128 + j];
    } else if (idx < OFF_DE_W2T) {
        int o = idx - OFF_DE_W1T, j = o >> 7, k = o & 127;
        v = de_w1[(k + ((j >= 256) ? 128 : 0)) * 256 + (j & 255)];
    } else if (idx < OFF_WGT) {
        int o = idx - OFF_DE_W2T, j = o >> 8, k = o & 255;
        v = de_w2[k * 128 + j];
    } else {
        int o = idx - OFF_WGT, j = o / 288, k = o - j * 288;
        int g = j >> 7, jj = j & 127;
        if (g == 0)
            v = (k < 128) ? w_ir[k * 128 + jj] : (k < 256) ? w_hr[(k - 128) * 128 + jj]
              : (k < 259) ? w_ir[(128 + k - 256) * 128 + jj] : 0.f;
        else if (g == 1)
            v = (k < 128) ? w_ii[k * 128 + jj] : (k < 256) ? w_hi[(k - 128) * 128 + jj]
              : (k < 259) ? w_ii[(128 + k - 256) * 128 + jj] : 0.f;
        else if (g == 2)
            v = (k < 128) ? w_in[k * 128 + jj]
              : (k >= 256 && k < 259) ? w_in[(128 + k - 256) * 128 + jj] : 0.f;
        else
            v = (k >= 128 && k < 256) ? w_hn[(k - 128) * 128 + jj] : 0.f;
    }
    g_wf16[idx] = (half_t)v;
}

// ---------------- per-batch barrier (8 participants, device scope) ----------
__device__ __forceinline__ void batch_barrier(int b, int phase, int tid) {
    __syncthreads();
    if (tid == 0) {
        __threadfence();   // release: flush h writes device-wide
        __hip_atomic_fetch_add(&g_bar[b], 1, __ATOMIC_RELEASE, __HIP_MEMORY_SCOPE_AGENT);
        while (__hip_atomic_load(&g_bar[b], __ATOMIC_ACQUIRE, __HIP_MEMORY_SCOPE_AGENT)
               < 8 * phase)
            __builtin_amdgcn_s_sleep(2);
    }
    __syncthreads();
    __threadfence();       // acquire: invalidate stale cached h lines
}

// ======================= fused kernel =======================
__global__ void __launch_bounds__(512, 2)
gnn_kernel(const float* __restrict__ enc_in, const float* __restrict__ dec_in,
           const float* __restrict__ enc_b1, const float* __restrict__ enc_b2,
           const float* __restrict__ pe_b1, const float* __restrict__ pe_b2,
           const float* __restrict__ pn_b1, const float* __restrict__ pn_b2,
           const float* __restrict__ de_b1, const float* __restrict__ de_b2,
           const float* __restrict__ b_ir, const float* __restrict__ b_ii,
           const float* __restrict__ b_in, float* __restrict__ out) {
    const int bid = blockIdx.x;
    const int b = bid & 15;            // batch
    const int sub = bid >> 4;          // 0..7, owns receivers sub*4 .. sub*4+3
    const int tid = threadIdx.x;
    const int wave = tid >> 6;
    const int lane = tid & 63;
    const int m16 = lane & 15, quad = lane >> 4;
    const int r0 = sub * 4;

    __shared__ __align__(16) unsigned char smem[105600];
    half_t* s_w2T = (half_t*)smem;                    // [128][LDK]   67584 B
    half_t* s_P   = (half_t*)(smem + 67584);          // [32][LDK]    16896 B
    half_t* s_Qb  = (half_t*)(smem + 84480);          // [4][LDK]      2112 B
    float*  s_h   = (float*)(smem + 86592);           // [32][LDH]    16896 B
    float*  s_msg = (float*)(smem + 103488);          // [4][LDH]      2112 B
    half_t* s_enc   = (half_t*)(smem + 86592);        // overlay s_h
    half_t* s_hid   = s_P;                            // overlays
    half_t* s_gates = s_P;

    int phase = 0;

    // ================= encoder (redundant per sub-block) =================
    for (int i = tid; i < 32 * LDE; i += 512) {
        const int s = i / LDE, k = i - s * LDE;
        s_enc[i] = (half_t)((k < 150) ? enc_in[((size_t)b * 32 + s) * 150 + k] : 0.f);
    }
    __syncthreads();
    // l1: [32x256], K=160
    #pragma unroll
    for (int i = 0; i < 4; ++i) {
        const int ti = wave + i * 8;
        const int nt = ti & 15, mt = ti >> 4;
        f32x4 acc = (f32x4)(0.f);
        #pragma unroll
        for (int k = 0; k < 5; ++k) {
            half8 a  = *(const half8*)&s_enc[(mt * 16 + m16) * LDE + k * 32 + quad * 8];
            half8 bf = *(const half8*)&g_wf16[OFF_ENC_W1T + (nt * 16 + m16) * 160 + k * 32 + quad * 8];
            acc = MFMA(a, bf, acc);
        }
        const int j = nt * 16 + m16;
        const float bj = enc_b1[j];
        #pragma unroll
        for (int g = 0; g < 4; ++g)
            s_hid[(mt * 16 + quad * 4 + g) * LDK + j] = (half_t)fmaxf(acc[g] + bj, 0.f);
    }
    __syncthreads();
    // l2: [32x128], K=256; keep own 4 rows -> g_hbuf[0]
    {
        float* h0 = g_hbuf + (size_t)b * 32 * LDH;    // parity 0
        #pragma unroll
        for (int i = 0; i < 2; ++i) {
            const int ti = wave + i * 8;
            const int nt = ti & 7, mt = ti >> 3;
            f32x4 acc = (f32x4)(0.f);
            #pragma unroll
            for (int k = 0; k < 8; ++k) {
                half8 a  = *(const half8*)&s_hid[(mt * 16 + m16) * LDK + k * 32 + quad * 8];
                half8 bf = *(const half8*)&g_wf16[OFF_ENC_W2T + (nt * 16 + m16) * 256 + k * 32 + quad * 8];
                acc = MFMA(a, bf, acc);
            }
            if (mt == (sub >> 2) && quad == (sub & 3)) {
                const int j = nt * 16 + m16;
                const float bj = enc_b2[j];
                #pragma unroll
                for (int g = 0; g < 4; ++g)
                    h0[(r0 + g) * LDH + j] = fmaxf(acc[g] + bj, 0.f);
            }
        }
    }
    ++phase; batch_barrier(b, phase, tid);

    // stage pe_w2T into LDS
    for (int i = tid; i < 128 * 32; i += 512) {
        const int row = i >> 5, c = i & 31;
        *(half8*)&s_w2T[row * LDK + c * 8] =
            *(const half8*)&g_wf16[OFF_PE_W2T + row * 256 + c * 8];
    }

    int p = 0;   // h parity
    const int qmt = sub >> 2, qquad = sub & 3;

    // ================= 2 passing rounds + 25 GRU steps =================
    for (int step = 0; step < 2 + TSTEPS; ++step) {
        const bool is_dec = (step >= 2);
        const int t = step - 2;
        if (step == 2) {   // swap LDS w2T to decoder edge weights
            for (int i = tid; i < 128 * 32; i += 512) {
                const int row = i >> 5, c = i & 31;
                *(half8*)&s_w2T[row * LDK + c * 8] =
                    *(const half8*)&g_wf16[OFF_DE_W2T + row * 256 + c * 8];
            }
        }
        // load h from global ping-pong into LDS
        {
            const float* hsrc = g_hbuf + ((size_t)p * 16 + b) * 32 * LDH;
            for (int i = tid; i < 32 * 32; i += 512) {
                const int row = i >> 5, c = i & 31;
                *(f32x4*)&s_h[row * LDH + c * 4] = *(const f32x4*)&hsrc[row * LDH + c * 4];
            }
        }
        __syncthreads();

        // ---- P (full) / Qb (own rows) ----
        {
            const half_t* w1T = g_wf16 + (is_dec ? OFF_DE_W1T : OFF_PE_W1T);
            const float* b1 = is_dec ? de_b1 : pe_b1;
            half8 a[2][4];
            #pragma unroll
            for (int mt = 0; mt < 2; ++mt)
                #pragma unroll
                for (int k = 0; k < 4; ++k)
                    a[mt][k] = frag_from_f32(&s_h[(mt * 16 + m16) * LDH + k * 32 + quad * 8]);
            #pragma unroll
            for (int i = 0; i < 6; ++i) {
                const int ti = wave + 8 * i;          // 0..47
                const bool isQ = ti >= 32;
                const int nt = isQ ? (ti - 16) : (ti & 15);
                const int mt = isQ ? qmt : (ti >> 4);
                f32x4 acc = (f32x4)(0.f);
                #pragma unroll
                for (int k = 0; k < 4; ++k) {
                    half8 bf = *(const half8*)&w1T[(nt * 16 + m16) * 128 + k * 32 + quad * 8];
                    acc = MFMA(a[mt][k], bf, acc);
                }
                const int j = nt * 16 + m16;
                if (!isQ) {
                    #pragma unroll
                    for (int g = 0; g < 4; ++g)
                        s_P[(mt * 16 + quad * 4 + g) * LDK + j] = (half_t)acc[g];
                } else if (quad == qquad) {
                    const float bj = b1[j - 256];
                    #pragma unroll
                    for (int g = 0; g < 4; ++g)
                        s_Qb[g * LDK + (j - 256)] = (half_t)(acc[g] + bj);
                }
            }
        }
        __syncthreads();

        // ---- edge layer2 + relu + mean (2 waves per receiver) ----
        {
            const float* b2 = is_dec ? de_b2 : pe_b2;
            const int rl = wave >> 1;
            const int r = r0 + rl;
            const int nh = wave & 1;
            half8 qb[8];
            #pragma unroll
            for (int k = 0; k < 8; ++k)
                qb[k] = *(const half8*)&s_Qb[rl * LDK + k * 32 + quad * 8];
            half8 A[2][8];
            #pragma unroll
            for (int mt = 0; mt < 2; ++mt) {
                const int s = mt * 16 + m16;
                const bool dz = (s == r);
                #pragma unroll
                for (int k = 0; k < 8; ++k) {
                    half8 pv = *(const half8*)&s_P[s * LDK + k * 32 + quad * 8];
                    half8 hv = relu8(pv + qb[k]);
                    A[mt][k] = dz ? h8zero() : hv;
                }
            }
            #pragma unroll
            for (int ni = 0; ni < 4; ++ni) {
                const int n = nh * 4 + ni;
                f32x4 acc0 = (f32x4)(0.f), acc1 = (f32x4)(0.f);
                #pragma unroll
                for (int k = 0; k < 8; ++k) {
                    half8 bf = *(const half8*)&s_w2T[(n * 16 + m16) * LDK + k * 32 + quad * 8];
                    acc0 = MFMA(A[0][k], bf, acc0);
                    acc1 = MFMA(A[1][k], bf, acc1);
                }
                const float b2n = b2[n * 16 + m16];
                float pp = 0.f;
                #pragma unroll
                for (int g = 0; g < 4; ++g)
                    pp += fmaxf(acc0[g] + b2n, 0.f) + fmaxf(acc1[g] + b2n, 0.f);
                pp += __shfl_xor(pp, 16);
                pp += __shfl_xor(pp, 32);
                if (quad == 0)
                    s_msg[rl * LDH + n * 16 + m16] = (pp - fmaxf(b2n, 0.f)) * (1.f / 31.f);
            }
        }
        __syncthreads();

        float* h_next = g_hbuf + ((size_t)(p ^ 1) * 16 + b) * 32 * LDH;

        if (!is_dec) {
            // ---- node MLP on own 4 msg rows (M=4) ----
            const int mrow = (m16 < 4) ? m16 : 0;
            half8 afr[4];
            #pragma unroll
            for (int k = 0; k < 4; ++k)
                afr[k] = frag_from_f32(&s_msg[mrow * LDH + k * 32 + quad * 8]);
            #pragma unroll
            for (int i = 0; i < 2; ++i) {
                const int nt = wave + i * 8;
                f32x4 acc = (f32x4)(0.f);
                #pragma unroll
                for (int k = 0; k < 4; ++k) {
                    half8 bf = *(const half8*)&g_wf16[OFF_PN_W1T + (nt * 16 + m16) * 128 + k * 32 + quad * 8];
                    acc = MFMA(afr[k], bf, acc);
                }
                if (quad == 0) {
                    const int j = nt * 16 + m16;
                    const float bj = pn_b1[j];
                    #pragma unroll
                    for (int g = 0; g < 4; ++g)
                        s_hid[g * LDK + j] = (half_t)fmaxf(acc[g] + bj, 0.f);
                }
            }
            __syncthreads();
            half8 ah[8];
            #pragma unroll
            for (int k = 0; k < 8; ++k)
                ah[k] = *(const half8*)&s_hid[mrow * LDK + k * 32 + quad * 8];
            {
                const int nt = wave;
                f32x4 acc = (f32x4)(0.f);
                #pragma unroll
                for (int k = 0; k < 8; ++k) {
                    half8 bf = *(const half8*)&g_wf16[OFF_PN_W2T + (nt * 16 + m16) * 256 + k * 32 + quad * 8];
                    acc = MFMA(ah[k], bf, acc);
                }
                if (quad == 0) {
                    const int j = nt * 16 + m16;
                    const float bj = pn_b2[j];
                    #pragma unroll
                    for (int g = 0; g < 4; ++g)
                        h_next[(r0 + g) * LDH + j] = fmaxf(acc[g] + bj, 0.f);
                }
            }
        } else {
            // ---- GRU gate GEMM (M=4, own rows) ----
            const float* dec_row = dec_in + ((size_t)(t * 16 + b) * 32 + r0) * 3;
            const int mrow = (m16 < 4) ? m16 : 0;
            half8 afr[9];
            #pragma unroll
            for (int k = 0; k < 4; ++k)
                afr[k] = frag_from_f32(&s_msg[mrow * LDH + k * 32 + quad * 8]);
            #pragma unroll
            for (int k = 0; k < 4; ++k)
                afr[4 + k] = frag_from_f32(&s_h[(r0 + mrow) * LDH + k * 32 + quad * 8]);
            {
                half8 tt = h8zero();
                if (quad == 0 && m16 < 4) {
                    tt[0] = (half_t)dec_row[mrow * 3 + 0];
                    tt[1] = (half_t)dec_row[mrow * 3 + 1];
                    tt[2] = (half_t)dec_row[mrow * 3 + 2];
                }
                afr[8] = tt;
            }
            #pragma unroll
            for (int i = 0; i < 4; ++i) {
                const int nt = wave + i * 8;       // 0..31
                const int g = nt >> 3;
                f32x4 acc = (f32x4)(0.f);
                #pragma unroll
                for (int k = 0; k < 9; ++k) {
                    const bool use = (g <= 1) || (g == 2 && (k < 4 || k == 8))
                                              || (g == 3 && k >= 4 && k < 8);
                    if (use) {
                        half8 bf = *(const half8*)&g_wf16[OFF_WGT + (nt * 16 + m16) * 288 + k * 32 + quad * 8];
                        acc = MFMA(afr[k], bf, acc);
                    }
                }
                if (quad == 0) {
                    const int j = nt * 16 + m16;
                    #pragma unroll
                    for (int gg = 0; gg < 4; ++gg)
                        s_gates[gg * LDG + j] = (half_t)acc[gg];
                }
            }
            __syncthreads();
            // ---- GRU epilogue: one output per thread ----
            {
                const int ri = tid >> 7;           // 0..3
                const int j = tid & 127;
                const int r = r0 + ri;
                const float rsv = (float)s_gates[ri * LDG + j] + b_ir[j];
                const float isv = (float)s_gates[ri * LDG + 128 + j] + b_ii[j];
                const float nsv = (float)s_gates[ri * LDG + 256 + j] + b_in[j];
                const float hnv = (float)s_gates[ri * LDG + 384 + j];
                const float rr = 1.f / (1.f + __expf(-rsv));
                const float ii = 1.f / (1.f + __expf(-isv));
                const float nn = tanhf(nsv + rr * hnv);
                const float hnew = (1.f - ii) * nn + ii * s_h[r * LDH + j];
                h_next[r * LDH + j] = hnew;
                out[(size_t)t * ROWS * 128 + ((size_t)b * 32 + r) * 128 + j] = hnew;
                if (t == TSTEPS - 1)
                    out[(size_t)TSTEPS * ROWS * 128 + ((size_t)b * 32 + r) * 128 + j] = hnew;
            }
        }
        p ^= 1;
        if (step < 2 + TSTEPS - 1) { ++phase; batch_barrier(b, phase, tid); }
    }
}

extern "C" void kernel_launch(void* const* d_in, const int* in_sizes, int n_in,
                              void* d_out, int out_size, void* d_ws, size_t ws_size,
                              hipStream_t stream) {
    const float* enc_in = (const float*)d_in[0];
    const float* dec_in = (const float*)d_in[1];
    // d_in[2], d_in[3] = R, S incidence: fully-connected, not needed.
    const float* enc_w1 = (const float*)d_in[4];
    const float* enc_b1 = (const float*)d_in[5];
    const float* enc_w2 = (const float*)d_in[6];
    const float* enc_b2 = (const float*)d_in[7];
    const float* pe_w1 = (const float*)d_in[8];
    const float* pe_b1 = (const float*)d_in[9];
    const float* pe_w2 = (const float*)d_in[10];
    const float* pe_b2 = (const float*)d_in[11];
    const float* pn_w1 = (const float*)d_in[12];
    const float* pn_b1 = (const float*)d_in[13];
    const float* pn_w2 = (const float*)d_in[14];
    const float* pn_b2 = (const float*)d_in[15];
    const float* de_w1 = (const float*)d_in[16];
    const float* de_b1 = (const float*)d_in[17];
    const float* de_w2 = (const float*)d_in[18];
    const float* de_b2 = (const float*)d_in[19];
    const float* w_hr = (const float*)d_in[20];
    const float* w_hi = (const float*)d_in[21];
    const float* w_hn = (const float*)d_in[22];
    const float* w_ir = (const float*)d_in[23];
    const float* b_ir = (const float*)d_in[24];
    const float* w_ii = (const float*)d_in[25];
    const float* b_ii = (const float*)d_in[26];
    const float* w_in = (const float*)d_in[27];
    const float* b_in = (const float*)d_in[28];
    (void)d_ws; (void)ws_size; (void)in_sizes; (void)n_in;

    convert_kernel<<<(WTOTAL + 255) / 256, 256, 0, stream>>>(
        enc_w1, enc_w2, pe_w1, pe_w2, pn_w1, pn_w2, de_w1, de_w2,
        w_hr, w_hi, w_hn, w_ir, w_ii, w_in);

    gnn_kernel<<<128, 512, 0, stream>>>(
        enc_in, dec_in, enc_b1, enc_b2, pe_b1, pe_b2, pn_b1, pn_b2,
        de_b1, de_b2, b_ir, b_ii, b_in, (float*)d_out);
}

// Round 7
// 1284.793 us; speedup vs baseline: 2.0878x; 2.0878x over previous
//
#include <hip/hip_runtime.h>

// GNN encoder + GRU decoder. R7: R6's validated MFMA step body, but each phase
// is its OWN LAUNCH (29 total) instead of a persistent kernel with device-scope
// atomic barriers. R6 measured ~97us/step with barriers vs ~2-4us/step of
// actual work: agent-scope fence L2 flush + one-cacheline spin serialization
// was the killer. Launch boundaries give free global sync at ~2-3us each.
// h state ping-pongs via g_hbuf, parity passed as kernel arg.

#define NJ 32
#define ROWS 512
#define TSTEPS 25
#define LDH 132          // f32 row stride
#define LDK 264          // half row stride (256-wide)
#define LDE 168          // half row stride, encoder input
#define LDG 520          // half row stride, gates

typedef _Float16 half_t;
typedef __attribute__((ext_vector_type(8))) _Float16 half8;
typedef __attribute__((ext_vector_type(8))) short short8;
typedef __attribute__((ext_vector_type(4))) float f32x4;

#define OFF_ENC_W1T 0          // [256 j][160 k]
#define OFF_ENC_W2T 40960      // [128 j][256 k]
#define OFF_PE_W1T  73728      // [512 j][128 k]  (j<256: P, j>=256: Q)
#define OFF_PE_W2T  139264     // [128 j][256 k]
#define OFF_PN_W1T  172032     // [256 j][128 k]
#define OFF_PN_W2T  204800     // [128 j][256 k]
#define OFF_DE_W1T  237568     // [512 j][128 k]
#define OFF_DE_W2T  303104     // [128 j][256 k]
#define OFF_WGT     335872     // [512 j][288 k]
#define WTOTAL      483328

__device__ __align__(16) half_t g_wf16[WTOTAL];
__device__ __align__(16) float g_hbuf[2 * 16 * 32 * LDH];   // ping-pong h

__device__ __forceinline__ half8 h8zero() {
    half8 z;
    #pragma unroll
    for (int e = 0; e < 8; ++e) z[e] = (half_t)0.f;
    return z;
}
__device__ __forceinline__ half8 relu8(half8 x) {
    short8 s = *(short8*)&x;
    short8 m = s >> 15;
    s = s & ~m;
    return *(half8*)&s;
}
__device__ __forceinline__ half8 frag_from_f32(const float* base) {
    f32x4 a = *(const f32x4*)base;
    f32x4 c = *(const f32x4*)(base + 4);
    half8 h;
    #pragma unroll
    for (int e = 0; e < 4; ++e) { h[e] = (half_t)a[e]; h[4 + e] = (half_t)c[e]; }
    return h;
}
#define MFMA(a, b, c) __builtin_amdgcn_mfma_f32_16x16x32_f16((a), (b), (c), 0, 0, 0)

// ---------------- weight conversion (once per call) ----------
__global__ void convert_kernel(const float* __restrict__ enc_w1, const float* __restrict__ enc_w2,
                               const float* __restrict__ pe_w1, const float* __restrict__ pe_w2,
                               const float* __restrict__ pn_w1, const float* __restrict__ pn_w2,
                               const float* __restrict__ de_w1, const float* __restrict__ de_w2,
                               const float* __restrict__ w_hr, const float* __restrict__ w_hi,
                               const float* __restrict__ w_hn, const float* __restrict__ w_ir,
                               const float* __restrict__ w_ii, const float* __restrict__ w_in) {
    const int idx = blockIdx.x * 256 + threadIdx.x;
    if (idx >= WTOTAL) return;
    float v = 0.f;
    if (idx < OFF_ENC_W2T) {
        int o = idx, j = o / 160, k = o - j * 160;
        v = (k < 150) ? enc_w1[k * 256 + j] : 0.f;
    } else if (idx < OFF_PE_W1T) {
        int o = idx - OFF_ENC_W2T, j = o >> 8, k = o & 255;
        v = enc_w2[k * 128 + j];
    } else if (idx < OFF_PE_W2T) {
        int o = idx - OFF_PE_W1T, j = o >> 7, k = o & 127;
        v = pe_w1[(k + ((j >= 256) ? 128 : 0)) * 256 + (j & 255)];
    } else if (idx < OFF_PN_W1T) {
        int o = idx - OFF_PE_W2T, j = o >> 8, k = o & 255;
        v = pe_w2[k * 128 + j];
    } else if (idx < OFF_PN_W2T) {
        int o = idx - OFF_PN_W1T, j = o >> 7, k = o & 127;
        v = pn_w1[k * 256 + j];
    } else if (idx < OFF_DE_W1T) {
        int o = idx - OFF_PN_W2T, j = o >> 8, k = o & 255;
        v = pn_w2[k * 128 + j];
    } else if (idx < OFF_DE_W2T) {
        int o = idx - OFF_DE_W1T, j = o >> 7, k = o & 127;
        v = de_w1[(k + ((j >= 256) ? 128 : 0)) * 256 + (j & 255)];
    } else if (idx < OFF_WGT) {
        int o = idx - OFF_DE_W2T, j = o >> 8, k = o & 255;
        v = de_w2[k * 128 + j];
    } else {
        int o = idx - OFF_WGT, j = o / 288, k = o - j * 288;
        int g = j >> 7, jj = j & 127;
        if (g == 0)
            v = (k < 128) ? w_ir[k * 128 + jj] : (k < 256) ? w_hr[(k - 128) * 128 + jj]
              : (k < 259) ? w_ir[(128 + k - 256) * 128 + jj] : 0.f;
        else if (g == 1)
            v = (k < 128) ? w_ii[k * 128 + jj] : (k < 256) ? w_hi[(k - 128) * 128 + jj]
              : (k < 259) ? w_ii[(128 + k - 256) * 128 + jj] : 0.f;
        else if (g == 2)
            v = (k < 128) ? w_in[k * 128 + jj]
              : (k >= 256 && k < 259) ? w_in[(128 + k - 256) * 128 + jj] : 0.f;
        else
            v = (k >= 128 && k < 256) ? w_hn[(k - 128) * 128 + jj] : 0.f;
    }
    g_wf16[idx] = (half_t)v;
}

// ---------------- encoder MLP (grid 128, each block writes own 4 rows) ------
__global__ void __launch_bounds__(512, 2)
encoder_kernel(const float* __restrict__ enc_in,
               const float* __restrict__ enc_b1, const float* __restrict__ enc_b2) {
    const int bid = blockIdx.x;
    const int b = bid & 15;
    const int sub = bid >> 4;
    const int tid = threadIdx.x;
    const int wave = tid >> 6;
    const int lane = tid & 63;
    const int m16 = lane & 15, quad = lane >> 4;
    const int r0 = sub * 4;

    __shared__ __align__(16) half_t s_enc[32 * LDE];
    __shared__ __align__(16) half_t s_hid[32 * LDK];

    for (int i = tid; i < 32 * LDE; i += 512) {
        const int s = i / LDE, k = i - s * LDE;
        s_enc[i] = (half_t)((k < 150) ? enc_in[((size_t)b * 32 + s) * 150 + k] : 0.f);
    }
    __syncthreads();
    // l1: [32x256], K=160
    #pragma unroll
    for (int i = 0; i < 4; ++i) {
        const int ti = wave + i * 8;
        const int nt = ti & 15, mt = ti >> 4;
        f32x4 acc = (f32x4)(0.f);
        #pragma unroll
        for (int k = 0; k < 5; ++k) {
            half8 a  = *(const half8*)&s_enc[(mt * 16 + m16) * LDE + k * 32 + quad * 8];
            half8 bf = *(const half8*)&g_wf16[OFF_ENC_W1T + (nt * 16 + m16) * 160 + k * 32 + quad * 8];
            acc = MFMA(a, bf, acc);
        }
        const int j = nt * 16 + m16;
        const float bj = enc_b1[j];
        #pragma unroll
        for (int g = 0; g < 4; ++g)
            s_hid[(mt * 16 + quad * 4 + g) * LDK + j] = (half_t)fmaxf(acc[g] + bj, 0.f);
    }
    __syncthreads();
    // l2: [32x128], K=256; keep own 4 rows -> g_hbuf parity 0
    float* h0 = g_hbuf + (size_t)b * 32 * LDH;
    #pragma unroll
    for (int i = 0; i < 2; ++i) {
        const int ti = wave + i * 8;
        const int nt = ti & 7, mt = ti >> 3;
        f32x4 acc = (f32x4)(0.f);
        #pragma unroll
        for (int k = 0; k < 8; ++k) {
            half8 a  = *(const half8*)&s_hid[(mt * 16 + m16) * LDK + k * 32 + quad * 8];
            half8 bf = *(const half8*)&g_wf16[OFF_ENC_W2T + (nt * 16 + m16) * 256 + k * 32 + quad * 8];
            acc = MFMA(a, bf, acc);
        }
        if (mt == (sub >> 2) && quad == (sub & 3)) {
            const int j = nt * 16 + m16;
            const float bj = enc_b2[j];
            #pragma unroll
            for (int g = 0; g < 4; ++g)
                h0[(r0 + g) * LDH + j] = fmaxf(acc[g] + bj, 0.f);
        }
    }
}

// ---------------- one step: P/Q -> edge -> (node MLP | GRU) -----------------
// grid 128 (16 batches x 8 subs, 4 receivers each), 512 threads.
template <int IS_DEC>
__global__ void __launch_bounds__(512, 2)
pass_kernel(int parity, int t,
            const float* __restrict__ b1, const float* __restrict__ b2,
            const float* __restrict__ pn_b1, const float* __restrict__ pn_b2,
            const float* __restrict__ b_ir, const float* __restrict__ b_ii,
            const float* __restrict__ b_in,
            const float* __restrict__ dec_in, float* __restrict__ out) {
    const int bid = blockIdx.x;
    const int b = bid & 15;
    const int sub = bid >> 4;
    const int tid = threadIdx.x;
    const int wave = tid >> 6;
    const int lane = tid & 63;
    const int m16 = lane & 15, quad = lane >> 4;
    const int r0 = sub * 4;
    const int qmt = sub >> 2, qquad = sub & 3;

    __shared__ __align__(16) unsigned char smem[105600];
    half_t* s_w2T = (half_t*)smem;                    // [128][LDK]
    half_t* s_P   = (half_t*)(smem + 67584);          // [32][LDK]
    half_t* s_Qb  = (half_t*)(smem + 84480);          // [4][LDK]
    float*  s_h   = (float*)(smem + 86592);           // [32][LDH]
    float*  s_msg = (float*)(smem + 103488);          // [4][LDH]
    half_t* s_hid   = s_P;
    half_t* s_gates = s_P;

    // stage w2T (edge layer-2 weights) into LDS
    for (int i = tid; i < 128 * 32; i += 512) {
        const int row = i >> 5, c = i & 31;
        *(half8*)&s_w2T[row * LDK + c * 8] =
            *(const half8*)&g_wf16[(IS_DEC ? OFF_DE_W2T : OFF_PE_W2T) + row * 256 + c * 8];
    }
    // load h
    {
        const float* hsrc = g_hbuf + ((size_t)parity * 16 + b) * 32 * LDH;
        for (int i = tid; i < 32 * 32; i += 512) {
            const int row = i >> 5, c = i & 31;
            *(f32x4*)&s_h[row * LDH + c * 4] = *(const f32x4*)&hsrc[row * LDH + c * 4];
        }
    }
    __syncthreads();

    // ---- P (full) / Qb (own rows) ----
    {
        const half_t* w1T = g_wf16 + (IS_DEC ? OFF_DE_W1T : OFF_PE_W1T);
        half8 a[2][4];
        #pragma unroll
        for (int mt = 0; mt < 2; ++mt)
            #pragma unroll
            for (int k = 0; k < 4; ++k)
                a[mt][k] = frag_from_f32(&s_h[(mt * 16 + m16) * LDH + k * 32 + quad * 8]);
        #pragma unroll
        for (int i = 0; i < 6; ++i) {
            const int ti = wave + 8 * i;          // 0..47
            const bool isQ = ti >= 32;
            const int nt = isQ ? (ti - 16) : (ti & 15);
            const int mt = isQ ? qmt : (ti >> 4);
            f32x4 acc = (f32x4)(0.f);
            #pragma unroll
            for (int k = 0; k < 4; ++k) {
                half8 bf = *(const half8*)&w1T[(nt * 16 + m16) * 128 + k * 32 + quad * 8];
                acc = MFMA(a[mt][k], bf, acc);
            }
            const int j = nt * 16 + m16;
            if (!isQ) {
                #pragma unroll
                for (int g = 0; g < 4; ++g)
                    s_P[(mt * 16 + quad * 4 + g) * LDK + j] = (half_t)acc[g];
            } else if (quad == qquad) {
                const float bj = b1[j - 256];
                #pragma unroll
                for (int g = 0; g < 4; ++g)
                    s_Qb[g * LDK + (j - 256)] = (half_t)(acc[g] + bj);
            }
        }
    }
    __syncthreads();

    // ---- edge layer2 + relu + mean (2 waves per receiver) ----
    {
        const int rl = wave >> 1;
        const int r = r0 + rl;
        const int nh = wave & 1;
        half8 qb[8];
        #pragma unroll
        for (int k = 0; k < 8; ++k)
            qb[k] = *(const half8*)&s_Qb[rl * LDK + k * 32 + quad * 8];
        half8 A[2][8];
        #pragma unroll
        for (int mt = 0; mt < 2; ++mt) {
            const int s = mt * 16 + m16;
            const bool dz = (s == r);
            #pragma unroll
            for (int k = 0; k < 8; ++k) {
                half8 pv = *(const half8*)&s_P[s * LDK + k * 32 + quad * 8];
                half8 hv = relu8(pv + qb[k]);
                A[mt][k] = dz ? h8zero() : hv;
            }
        }
        #pragma unroll
        for (int ni = 0; ni < 4; ++ni) {
            const int n = nh * 4 + ni;
            f32x4 acc0 = (f32x4)(0.f), acc1 = (f32x4)(0.f);
            #pragma unroll
            for (int k = 0; k < 8; ++k) {
                half8 bf = *(const half8*)&s_w2T[(n * 16 + m16) * LDK + k * 32 + quad * 8];
                acc0 = MFMA(A[0][k], bf, acc0);
                acc1 = MFMA(A[1][k], bf, acc1);
            }
            const float b2n = b2[n * 16 + m16];
            float pp = 0.f;
            #pragma unroll
            for (int g = 0; g < 4; ++g)
                pp += fmaxf(acc0[g] + b2n, 0.f) + fmaxf(acc1[g] + b2n, 0.f);
            pp += __shfl_xor(pp, 16);
            pp += __shfl_xor(pp, 32);
            if (quad == 0)
                s_msg[rl * LDH + n * 16 + m16] = (pp - fmaxf(b2n, 0.f)) * (1.f / 31.f);
        }
    }
    __syncthreads();

    float* h_next = g_hbuf + ((size_t)(parity ^ 1) * 16 + b) * 32 * LDH;

    if (!IS_DEC) {
        // ---- node MLP on own 4 msg rows (M=4) ----
        const int mrow = (m16 < 4) ? m16 : 0;
        half8 afr[4];
        #pragma unroll
        for (int k = 0; k < 4; ++k)
            afr[k] = frag_from_f32(&s_msg[mrow * LDH + k * 32 + quad * 8]);
        #pragma unroll
        for (int i = 0; i < 2; ++i) {
            const int nt = wave + i * 8;
            f32x4 acc = (f32x4)(0.f);
            #pragma unroll
            for (int k = 0; k < 4; ++k) {
                half8 bf = *(const half8*)&g_wf16[OFF_PN_W1T + (nt * 16 + m16) * 128 + k * 32 + quad * 8];
                acc = MFMA(afr[k], bf, acc);
            }
            if (quad == 0) {
                const int j = nt * 16 + m16;
                const float bj = pn_b1[j];
                #pragma unroll
                for (int g = 0; g < 4; ++g)
                    s_hid[g * LDK + j] = (half_t)fmaxf(acc[g] + bj, 0.f);
            }
        }
        __syncthreads();
        half8 ah[8];
        #pragma unroll
        for (int k = 0; k < 8; ++k)
            ah[k] = *(const half8*)&s_hid[mrow * LDK + k * 32 + quad * 8];
        {
            const int nt = wave;
            f32x4 acc = (f32x4)(0.f);
            #pragma unroll
            for (int k = 0; k < 8; ++k) {
                half8 bf = *(const half8*)&g_wf16[OFF_PN_W2T + (nt * 16 + m16) * 256 + k * 32 + quad * 8];
                acc = MFMA(ah[k], bf, acc);
            }
            if (quad == 0) {
                const int j = nt * 16 + m16;
                const float bj = pn_b2[j];
                #pragma unroll
                for (int g = 0; g < 4; ++g)
                    h_next[(r0 + g) * LDH + j] = fmaxf(acc[g] + bj, 0.f);
            }
        }
    } else {
        // ---- GRU gate GEMM (M=4, own rows) ----
        const float* dec_row = dec_in + ((size_t)(t * 16 + b) * 32 + r0) * 3;
        const int mrow = (m16 < 4) ? m16 : 0;
        half8 afr[9];
        #pragma unroll
        for (int k = 0; k < 4; ++k)
            afr[k] = frag_from_f32(&s_msg[mrow * LDH + k * 32 + quad * 8]);
        #pragma unroll
        for (int k = 0; k < 4; ++k)
            afr[4 + k] = frag_from_f32(&s_h[(r0 + mrow) * LDH + k * 32 + quad * 8]);
        {
            half8 tt = h8zero();
            if (quad == 0 && m16 < 4) {
                tt[0] = (half_t)dec_row[mrow * 3 + 0];
                tt[1] = (half_t)dec_row[mrow * 3 + 1];
                tt[2] = (half_t)dec_row[mrow * 3 + 2];
            }
            afr[8] = tt;
        }
        #pragma unroll
        for (int i = 0; i < 4; ++i) {
            const int nt = wave + i * 8;       // 0..31
            const int g = nt >> 3;
            f32x4 acc = (f32x4)(0.f);
            #pragma unroll
            for (int k = 0; k < 9; ++k) {
                const bool use = (g <= 1) || (g == 2 && (k < 4 || k == 8))
                                          || (g == 3 && k >= 4 && k < 8);
                if (use) {
                    half8 bf = *(const half8*)&g_wf16[OFF_WGT + (nt * 16 + m16) * 288 + k * 32 + quad * 8];
                    acc = MFMA(afr[k], bf, acc);
                }
            }
            if (quad == 0) {
                const int j = nt * 16 + m16;
                #pragma unroll
                for (int gg = 0; gg < 4; ++gg)
                    s_gates[gg * LDG + j] = (half_t)acc[gg];
            }
        }
        __syncthreads();
        // ---- GRU epilogue ----
        {
            const int ri = tid >> 7;           // 0..3
            const int j = tid & 127;
            const int r = r0 + ri;
            const float rsv = (float)s_gates[ri * LDG + j] + b_ir[j];
            const float isv = (float)s_gates[ri * LDG + 128 + j] + b_ii[j];
            const float nsv = (float)s_gates[ri * LDG + 256 + j] + b_in[j];
            const float hnv = (float)s_gates[ri * LDG + 384 + j];
            const float rr = 1.f / (1.f + __expf(-rsv));
            const float ii = 1.f / (1.f + __expf(-isv));
            const float nn = tanhf(nsv + rr * hnv);
            const float hnew = (1.f - ii) * nn + ii * s_h[r * LDH + j];
            h_next[r * LDH + j] = hnew;
            out[(size_t)t * ROWS * 128 + ((size_t)b * 32 + r) * 128 + j] = hnew;
            if (t == TSTEPS - 1)
                out[(size_t)TSTEPS * ROWS * 128 + ((size_t)b * 32 + r) * 128 + j] = hnew;
        }
    }
}

extern "C" void kernel_launch(void* const* d_in, const int* in_sizes, int n_in,
                              void* d_out, int out_size, void* d_ws, size_t ws_size,
                              hipStream_t stream) {
    const float* enc_in = (const float*)d_in[0];
    const float* dec_in = (const float*)d_in[1];
    // d_in[2], d_in[3] = R, S incidence: fully-connected, not needed.
    const float* enc_w1 = (const float*)d_in[4];
    const float* enc_b1 = (const float*)d_in[5];
    const float* enc_w2 = (const float*)d_in[6];
    const float* enc_b2 = (const float*)d_in[7];
    const float* pe_w1 = (const float*)d_in[8];
    const float* pe_b1 = (const float*)d_in[9];
    const float* pe_w2 = (const float*)d_in[10];
    const float* pe_b2 = (const float*)d_in[11];
    const float* pn_w1 = (const float*)d_in[12];
    const float* pn_b1 = (const float*)d_in[13];
    const float* pn_w2 = (const float*)d_in[14];
    const float* pn_b2 = (const float*)d_in[15];
    const float* de_w1 = (const float*)d_in[16];
    const float* de_b1 = (const float*)d_in[17];
    const float* de_w2 = (const float*)d_in[18];
    const float* de_b2 = (const float*)d_in[19];
    const float* w_hr = (const float*)d_in[20];
    const float* w_hi = (const float*)d_in[21];
    const float* w_hn = (const float*)d_in[22];
    const float* w_ir = (const float*)d_in[23];
    const float* b_ir = (const float*)d_in[24];
    const float* w_ii = (const float*)d_in[25];
    const float* b_ii = (const float*)d_in[26];
    const float* w_in = (const float*)d_in[27];
    const float* b_in = (const float*)d_in[28];
    (void)d_ws; (void)ws_size; (void)in_sizes; (void)n_in;

    convert_kernel<<<(WTOTAL + 255) / 256, 256, 0, stream>>>(
        enc_w1, enc_w2, pe_w1, pe_w2, pn_w1, pn_w2, de_w1, de_w2,
        w_hr, w_hi, w_hn, w_ir, w_ii, w_in);

    encoder_kernel<<<128, 512, 0, stream>>>(enc_in, enc_b1, enc_b2);

    int p = 0;
    for (int pass = 0; pass < 2; ++pass) {
        pass_kernel<0><<<128, 512, 0, stream>>>(p, 0, pe_b1, pe_b2, pn_b1, pn_b2,
                                                nullptr, nullptr, nullptr,
                                                nullptr, nullptr);
        p ^= 1;
    }
    float* out = (float*)d_out;
    for (int t = 0; t < TSTEPS; ++t) {
        pass_kernel<1><<<128, 512, 0, stream>>>(p, t, de_b1, de_b2, nullptr, nullptr,
                                                b_ir, b_ii, b_in, dec_in, out);
        p ^= 1;
    }
}